// Round 11
// baseline (183.087 us; speedup 1.0000x reference)
//
#include <hip/hip_runtime.h>
#include <hip/hip_bf16.h>

#define D 64
#define RPB 256          // rows per bin bucket (row_local 8 bits)
#define RSH 8            // log2(RPB)
#define FPB 128          // rows per fused-pull block (half bucket)
#define CAP 2560         // edges per LDS sort chunk (20 KB)
#define NBMAX 1024       // max buckets; needs n_nodes <= 131072 (17-bit col)
#define CPAD 16          // ints per padded counter (64 B line)

// ===========================================================================
// support = x @ (W0+W1+W2), stored as bf16
// ===========================================================================
__global__ __launch_bounds__(256) void gemm_kernel(const float* __restrict__ x,
                                                   const float* __restrict__ w0,
                                                   const float* __restrict__ w1,
                                                   const float* __restrict__ w2,
                                                   __hip_bfloat16* __restrict__ support,
                                                   int n) {
    __shared__ float Ws[D * D];
    __shared__ float xs[4][D];

    for (int i = threadIdx.x; i < D * D; i += 256)
        Ws[i] = w0[i] + w1[i] + w2[i];
    __syncthreads();

    const int wid  = threadIdx.x >> 6;
    const int lane = threadIdx.x & 63;
    int row = blockIdx.x * 4 + wid;
    const int nw = gridDim.x * 4;

    for (; row < n; row += nw) {
        xs[wid][lane] = x[(size_t)row * D + lane];
        float acc = 0.0f;
#pragma unroll
        for (int k = 0; k < D; ++k) {
            acc += xs[wid][k] * Ws[k * D + lane];
        }
        support[(size_t)row * D + lane] = __float2bfloat16(acc);
    }
}

// f32-support variant for the fallback path
__global__ __launch_bounds__(256) void gemm_f32_kernel(const float* __restrict__ x,
                                                       const float* __restrict__ w0,
                                                       const float* __restrict__ w1,
                                                       const float* __restrict__ w2,
                                                       float* __restrict__ support,
                                                       int n) {
    __shared__ float Ws[D * D];
    __shared__ float xs[4][D];
    for (int i = threadIdx.x; i < D * D; i += 256)
        Ws[i] = w0[i] + w1[i] + w2[i];
    __syncthreads();
    const int wid  = threadIdx.x >> 6;
    const int lane = threadIdx.x & 63;
    int row = blockIdx.x * 4 + wid;
    const int nw = gridDim.x * 4;
    for (; row < n; row += nw) {
        xs[wid][lane] = x[(size_t)row * D + lane];
        float acc = 0.0f;
#pragma unroll
        for (int k = 0; k < D; ++k) acc += xs[wid][k] * Ws[k * D + lane];
        support[(size_t)row * D + lane] = acc;
    }
}

// ===========================================================================
// Binning (R9-proven): hist -> scan -> partition scatter, padded counters
// ===========================================================================
__global__ __launch_bounds__(256) void zero_kernel(int* __restrict__ p, int n) {
    int i = blockIdx.x * 256 + threadIdx.x;
    int stride = gridDim.x * 256;
    for (; i < n; i += stride) p[i] = 0;
}

__global__ __launch_bounds__(256) void bucket_hist_kernel(const int* __restrict__ rows,
                                                          int ne, int* __restrict__ gcnt,
                                                          int nb) {
    __shared__ int lcnt[NBMAX];
    for (int i = threadIdx.x; i < nb; i += 256) lcnt[i] = 0;
    __syncthreads();
    int i = blockIdx.x * 256 + threadIdx.x;
    int stride = gridDim.x * 256;
    for (; i < ne; i += stride) atomicAdd(&lcnt[rows[i] >> RSH], 1);
    __syncthreads();
    for (int b = threadIdx.x; b < nb; b += 256) {
        int c = lcnt[b];
        if (c) atomicAdd(&gcnt[b * CPAD], c);
    }
}

__global__ __launch_bounds__(256) void bucket_scan_kernel(const int* __restrict__ gcnt,
                                                          int nb,
                                                          int* __restrict__ base,
                                                          int* __restrict__ cursor) {
    __shared__ int ts[256];
    const int tid = threadIdx.x;
    int b0 = tid * 4;
    int v[4]; int tsum = 0;
#pragma unroll
    for (int j = 0; j < 4; ++j) {
        int idx = b0 + j;
        v[j] = (idx < nb) ? gcnt[idx * CPAD] : 0;
        tsum += v[j];
    }
    ts[tid] = tsum;
    __syncthreads();
    for (int off = 1; off < 256; off <<= 1) {
        int t = (tid >= off) ? ts[tid - off] : 0;
        __syncthreads();
        ts[tid] += t;
        __syncthreads();
    }
    int excl = ts[tid] - tsum;
#pragma unroll
    for (int j = 0; j < 4; ++j) {
        int idx = b0 + j;
        if (idx < nb) { base[idx] = excl; cursor[idx * CPAD] = excl; }
        excl += v[j];
    }
    if (tid == 255) base[nb] = excl;
}

__global__ __launch_bounds__(256) void bin_scatter_kernel(const int* __restrict__ rows,
                                                          const int* __restrict__ cols,
                                                          const float* __restrict__ vals,
                                                          int ne,
                                                          int* __restrict__ cursor,
                                                          int nb,
                                                          int2* __restrict__ binned) {
    __shared__ int lcnt[NBMAX];
    __shared__ int lbase[NBMAX];
    const int tid = threadIdx.x;
    const int ce = (ne + gridDim.x - 1) / gridDim.x;
    const int e0 = blockIdx.x * ce;
    const int e1 = min(ne, e0 + ce);

    for (int i = tid; i < nb; i += 256) lcnt[i] = 0;
    __syncthreads();
    for (int e = e0 + tid; e < e1; e += 256) atomicAdd(&lcnt[rows[e] >> RSH], 1);
    __syncthreads();
    for (int b = tid; b < nb; b += 256) {
        int c = lcnt[b];
        lbase[b] = c ? atomicAdd(&cursor[b * CPAD], c) : 0;
    }
    __syncthreads();
    for (int i = tid; i < nb; i += 256) lcnt[i] = 0;   // reuse as local cursor
    __syncthreads();
    for (int e = e0 + tid; e < e1; e += 256) {
        int r = rows[e];
        int b = r >> RSH;
        int loc = atomicAdd(&lcnt[b], 1);
        int2 cv;
        cv.x = ((r & (RPB - 1)) << 17) | cols[e];
        cv.y = __float_as_int(vals[e]);
        binned[lbase[b] + loc] = cv;
    }
}

// ===========================================================================
// Fused sort+pull: 2 blocks per bucket; block owns 128 rows (half bucket).
// Per <=CAP-edge chunk of the bucket segment: LDS hist(128) -> scan -> LDS
// counting-sort of THIS half's edges -> waves pull their rows (2 rows per
// 32-lane half, uint = 2 bf16 gather, register accumulate across chunks).
// Replaces local_csr + csr round-trip + pull2.
// ===========================================================================
__global__ __launch_bounds__(256) void fused_pull_kernel(const int* __restrict__ base,
                                                         const int2* __restrict__ binned,
                                                         const unsigned int* __restrict__ sup32,
                                                         const float* __restrict__ bias,
                                                         float* __restrict__ out, int n) {
    __shared__ int2 eds[CAP];          // 20 KB sorted edge buffer
    __shared__ int hist[FPB];
    __shared__ int pref[FPB];
    __shared__ int cur[FPB];

    const int tid  = threadIdx.x;
    const int b    = blockIdx.x >> 1;   // bucket
    const int hi   = blockIdx.x & 1;    // which half of the bucket
    const int jb   = base[b], je = base[b + 1];
    const int row0 = b * RPB + hi * FPB;

    const int lane = tid & 63;
    const int wv   = tid >> 6;          // 0..3
    const int half = lane >> 5;         // 0/1
    const int sub  = lane & 31;         // feature-pair index
    const float2 b2 = reinterpret_cast<const float2*>(bias)[sub];

    float ax[16], ay[16];
#pragma unroll
    for (int t = 0; t < 16; ++t) { ax[t] = 0.0f; ay[t] = 0.0f; }

    for (int c0 = jb; c0 < je; c0 += CAP) {
        const int c1 = min(je, c0 + CAP);

        // --- hist of this half's rows in the chunk ---
        for (int i = tid; i < FPB; i += 256) hist[i] = 0;
        __syncthreads();
        for (int j = c0 + tid; j < c1; j += 256) {
            int rl = binned[j].x >> 17;                 // 0..255
            if ((rl >> 7) == hi) atomicAdd(&hist[rl & (FPB - 1)], 1);
        }
        __syncthreads();

        // --- inclusive scan (Hillis-Steele over 128) ---
        if (tid < FPB) pref[tid] = hist[tid];
        __syncthreads();
        for (int off = 1; off < FPB; off <<= 1) {
            int t = (tid < FPB && tid >= off) ? pref[tid - off] : 0;
            __syncthreads();
            if (tid < FPB) pref[tid] += t;
            __syncthreads();
        }
        if (tid < FPB) cur[tid] = pref[tid] - hist[tid];   // exclusive start
        __syncthreads();

        // --- counting-sort scatter into eds ---
        for (int j = c0 + tid; j < c1; j += 256) {
            int2 e = binned[j];
            int rl = e.x >> 17;
            if ((rl >> 7) == hi) {
                int pos = atomicAdd(&cur[rl & (FPB - 1)], 1);
                int2 o; o.x = e.x & 0x1FFFF; o.y = e.y;
                eds[pos] = o;
            }
        }
        __syncthreads();

        // --- pull: wave wv handles rows wv*32 .. wv*32+31, 2 at a time ---
#pragma unroll
        for (int t = 0; t < 16; ++t) {
            const int rl = wv * 32 + 2 * t + half;          // 0..127
            const int js = pref[rl] - hist[rl];
            const int jeL = pref[rl];
            int j = js;
            for (; j + 1 < jeL; j += 2) {
                int2 e0 = eds[j], e1 = eds[j + 1];
                unsigned int u0 = sup32[(size_t)e0.x * 32 + sub];
                unsigned int u1 = sup32[(size_t)e1.x * 32 + sub];
                float v0 = __int_as_float(e0.y), v1 = __int_as_float(e1.y);
                ax[t] += v0 * __uint_as_float(u0 << 16);
                ay[t] += v0 * __uint_as_float(u0 & 0xffff0000u);
                ax[t] += v1 * __uint_as_float(u1 << 16);
                ay[t] += v1 * __uint_as_float(u1 & 0xffff0000u);
            }
            if (j < jeL) {
                int2 e = eds[j];
                unsigned int u = sup32[(size_t)e.x * 32 + sub];
                float v = __int_as_float(e.y);
                ax[t] += v * __uint_as_float(u << 16);
                ay[t] += v * __uint_as_float(u & 0xffff0000u);
            }
        }
        __syncthreads();   // protect eds/hist/pref before next chunk
    }

    // --- store ---
#pragma unroll
    for (int t = 0; t < 16; ++t) {
        int r = row0 + wv * 32 + 2 * t + half;
        if (r < n) {
            float2 o; o.x = ax[t] + b2.x; o.y = ay[t] + b2.y;
            reinterpret_cast<float2*>(out)[(size_t)r * 32 + sub] = o;
        }
    }
}

// ===========================================================================
// Fallback (R1, verified): bias-init + atomic scatter (f32 support)
// ===========================================================================
__global__ __launch_bounds__(256) void init_kernel(const float* __restrict__ bias,
                                                   float* __restrict__ out, int total4) {
    int i = blockIdx.x * 256 + threadIdx.x;
    int stride = gridDim.x * 256;
    for (; i < total4; i += stride) {
        int base4 = (i * 4) & (D - 1);
        float4 bv;
        bv.x = bias[base4 + 0]; bv.y = bias[base4 + 1];
        bv.z = bias[base4 + 2]; bv.w = bias[base4 + 3];
        reinterpret_cast<float4*>(out)[i] = bv;
    }
}

__global__ __launch_bounds__(256) void scatter_kernel(const int* __restrict__ rows,
                                                      const int* __restrict__ cols,
                                                      const float* __restrict__ vals,
                                                      const float* __restrict__ support,
                                                      float* __restrict__ out, int ne) {
    const int wid  = blockIdx.x * 4 + (threadIdx.x >> 6);
    const int lane = threadIdx.x & 63;
    const int nw = gridDim.x * 4;
    for (int e = wid; e < ne; e += nw) {
        const int r = rows[e];
        const int c = cols[e];
        const float v = vals[e];
        unsafeAtomicAdd(&out[(size_t)r * D + lane], v * support[(size_t)c * D + lane]);
    }
}

extern "C" void kernel_launch(void* const* d_in, const int* in_sizes, int n_in,
                              void* d_out, int out_size, void* d_ws, size_t ws_size,
                              hipStream_t stream) {
    const float* x         = (const float*)d_in[0];
    const int*   edge_rows = (const int*)d_in[1];
    const int*   edge_cols = (const int*)d_in[2];
    const float* edge_vals = (const float*)d_in[3];
    const float* w_own     = (const float*)d_in[4];
    const float* w_nbr     = (const float*)d_in[5];
    const float* w_temp    = (const float*)d_in[6];
    const float* bias      = (const float*)d_in[7];

    float* out = (float*)d_out;
    const int n_nodes = in_sizes[0] / D;
    const int n_edges = in_sizes[1];
    const int nb = (n_nodes + RPB - 1) / RPB;

    // ---- workspace layout ----
    char* ws = (char*)d_ws;
    size_t off = 0;
    auto take = [&](size_t bytes) -> char* {
        char* p = ws + off;
        off = (off + bytes + 15) & ~(size_t)15;
        return p;
    };
    __hip_bfloat16* support = (__hip_bfloat16*)take((size_t)n_nodes * D * sizeof(__hip_bfloat16));
    int2* binned = (int2*)take((size_t)n_edges * sizeof(int2));
    int*  gcnt   = (int*) take((size_t)nb * CPAD * sizeof(int));
    int*  base   = (int*) take((size_t)(nb + 1) * sizeof(int));
    int*  cursor = (int*) take((size_t)nb * CPAD * sizeof(int));
    const bool full_fits = (off <= ws_size) && (nb <= NBMAX) && (n_nodes <= (1 << 17));

    if (full_fits) {
        gemm_kernel<<<1024, 256, 0, stream>>>(x, w_own, w_nbr, w_temp, support, n_nodes);
        zero_kernel<<<32, 256, 0, stream>>>(gcnt, nb * CPAD);
        bucket_hist_kernel<<<1024, 256, 0, stream>>>(edge_rows, n_edges, gcnt, nb);
        bucket_scan_kernel<<<1, 256, 0, stream>>>(gcnt, nb, base, cursor);
        bin_scatter_kernel<<<512, 256, 0, stream>>>(edge_rows, edge_cols, edge_vals,
                                                    n_edges, cursor, nb, binned);
        fused_pull_kernel<<<nb * 2, 256, 0, stream>>>(base, binned,
                                                      (const unsigned int*)support,
                                                      bias, out, n_nodes);
    } else {
        // R1 fallback: f32 support + atomic scatter
        float* support_f = (float*)d_ws;
        gemm_f32_kernel<<<1024, 256, 0, stream>>>(x, w_own, w_nbr, w_temp, support_f, n_nodes);
        int total4 = (n_nodes * D) / 4;
        int blocks = (total4 + 255) / 256; if (blocks > 2048) blocks = 2048;
        init_kernel<<<blocks, 256, 0, stream>>>(bias, out, total4);
        scatter_kernel<<<2048, 256, 0, stream>>>(edge_rows, edge_cols, edge_vals,
                                                 support_f, out, n_edges);
    }
}

// Round 12
// 151.859 us; speedup vs baseline: 1.2056x; 1.2056x over previous
//
#include <hip/hip_runtime.h>
#include <hip/hip_bf16.h>

#define D 64
#define RPB 256          // rows per bucket (row_local 8 bits)
#define RSH 8            // log2(RPB)
#define NBMAX 512        // max buckets (n_nodes <= 131072 -> nb <= 512)
#define CPAD 16          // ints per padded counter (64 B line)
#define CAP 3200         // edges per LDS sort sub-chunk (25.6 KB)

// ===========================================================================
// support = x @ (W0+W1+W2), stored as bf16
// ===========================================================================
__global__ __launch_bounds__(256) void gemm_kernel(const float* __restrict__ x,
                                                   const float* __restrict__ w0,
                                                   const float* __restrict__ w1,
                                                   const float* __restrict__ w2,
                                                   __hip_bfloat16* __restrict__ support,
                                                   int n) {
    __shared__ float Ws[D * D];
    __shared__ float xs[4][D];

    for (int i = threadIdx.x; i < D * D; i += 256)
        Ws[i] = w0[i] + w1[i] + w2[i];
    __syncthreads();

    const int wid  = threadIdx.x >> 6;
    const int lane = threadIdx.x & 63;
    int row = blockIdx.x * 4 + wid;
    const int nw = gridDim.x * 4;

    for (; row < n; row += nw) {
        xs[wid][lane] = x[(size_t)row * D + lane];
        float acc = 0.0f;
#pragma unroll
        for (int k = 0; k < D; ++k) {
            acc += xs[wid][k] * Ws[k * D + lane];
        }
        support[(size_t)row * D + lane] = __float2bfloat16(acc);
    }
}

// f32-support variant for the fallback path
__global__ __launch_bounds__(256) void gemm_f32_kernel(const float* __restrict__ x,
                                                       const float* __restrict__ w0,
                                                       const float* __restrict__ w1,
                                                       const float* __restrict__ w2,
                                                       float* __restrict__ support,
                                                       int n) {
    __shared__ float Ws[D * D];
    __shared__ float xs[4][D];
    for (int i = threadIdx.x; i < D * D; i += 256)
        Ws[i] = w0[i] + w1[i] + w2[i];
    __syncthreads();
    const int wid  = threadIdx.x >> 6;
    const int lane = threadIdx.x & 63;
    int row = blockIdx.x * 4 + wid;
    const int nw = gridDim.x * 4;
    for (; row < n; row += nw) {
        xs[wid][lane] = x[(size_t)row * D + lane];
        float acc = 0.0f;
#pragma unroll
        for (int k = 0; k < D; ++k) acc += xs[wid][k] * Ws[k * D + lane];
        support[(size_t)row * D + lane] = acc;
    }
}

// ===========================================================================
// hist -> scan (padded counters, R9-proven)
// ===========================================================================
__global__ __launch_bounds__(256) void bucket_hist_kernel(const int* __restrict__ rows,
                                                          int ne, int* __restrict__ gcnt,
                                                          int nb) {
    __shared__ int lcnt[NBMAX];
    for (int i = threadIdx.x; i < nb; i += 256) lcnt[i] = 0;
    __syncthreads();
    int i = blockIdx.x * 256 + threadIdx.x;
    int stride = gridDim.x * 256;
    for (; i < ne; i += stride) atomicAdd(&lcnt[rows[i] >> RSH], 1);
    __syncthreads();
    for (int b = threadIdx.x; b < nb; b += 256) {
        int c = lcnt[b];
        if (c) atomicAdd(&gcnt[b * CPAD], c);
    }
}

__global__ __launch_bounds__(256) void bucket_scan_kernel(const int* __restrict__ gcnt,
                                                          int nb,
                                                          int* __restrict__ base,
                                                          int* __restrict__ cursor) {
    __shared__ int ts[256];
    const int tid = threadIdx.x;
    int b0 = tid * 2;
    int v0 = (b0 < nb)     ? gcnt[b0 * CPAD]       : 0;
    int v1 = (b0 + 1 < nb) ? gcnt[(b0 + 1) * CPAD] : 0;
    int tsum = v0 + v1;
    ts[tid] = tsum;
    __syncthreads();
    for (int off = 1; off < 256; off <<= 1) {
        int t = (tid >= off) ? ts[tid - off] : 0;
        __syncthreads();
        ts[tid] += t;
        __syncthreads();
    }
    int excl = ts[tid] - tsum;
    if (b0 < nb)     { base[b0] = excl;          cursor[b0 * CPAD] = excl; }
    if (b0 + 1 < nb) { base[b0 + 1] = excl + v0; cursor[(b0 + 1) * CPAD] = excl + v0; }
    if (tid == 255) base[nb] = excl + tsum;   // == total (last thread's inclusive)
}

// ===========================================================================
// bin_sort_scatter: per 3200-edge sub-chunk, counting-sort by bucket in LDS,
// then burst-write each bucket run contiguously (full-line writes). Replaces
// R9's per-edge scattered 8B writes (46us, 40MB writeback for 12.8MB payload).
// ===========================================================================
__global__ __launch_bounds__(256) void bin_sort_scatter_kernel(const int* __restrict__ rows,
                                                               const int* __restrict__ cols,
                                                               const float* __restrict__ vals,
                                                               int ne,
                                                               int* __restrict__ cursor,
                                                               int nb,
                                                               int2* __restrict__ binned) {
    __shared__ int2 sorted[CAP];        // 25.6 KB
    __shared__ int  pref[NBMAX];        // hist -> exclusive prefix
    __shared__ int  cur[NBMAX];         // running cursor -> inclusive prefix
    __shared__ int  lbase[NBMAX];       // global run base per bucket
    __shared__ int  ts[256];
    const int tid = threadIdx.x;
    const int ce = (ne + gridDim.x - 1) / gridDim.x;
    const int e0 = blockIdx.x * ce;
    const int e1 = min(ne, e0 + ce);

    for (int c0 = e0; c0 < e1; c0 += CAP) {
        const int c1 = min(e1, c0 + CAP);
        const int cnt = c1 - c0;

        // --- hist into pref ---
        pref[2 * tid] = 0; pref[2 * tid + 1] = 0;
        __syncthreads();
        for (int e = c0 + tid; e < c1; e += 256)
            atomicAdd(&pref[rows[e] >> RSH], 1);
        __syncthreads();

        // --- in-place exclusive scan over 512 slots (2 per thread) ---
        int a0 = pref[2 * tid], a1 = pref[2 * tid + 1];
        int tsum = a0 + a1;
        ts[tid] = tsum;
        __syncthreads();
        for (int off = 1; off < 256; off <<= 1) {
            int t = (tid >= off) ? ts[tid - off] : 0;
            __syncthreads();
            ts[tid] += t;
            __syncthreads();
        }
        int excl = ts[tid] - tsum;
        pref[2 * tid] = excl;           pref[2 * tid + 1] = excl + a0;
        cur[2 * tid]  = excl;           cur[2 * tid + 1]  = excl + a0;
        // --- reserve global runs (padded cursors; slots >= nb have a==0) ---
        lbase[2 * tid]     = a0 ? atomicAdd(&cursor[(2 * tid) * CPAD], a0) : 0;
        lbase[2 * tid + 1] = a1 ? atomicAdd(&cursor[(2 * tid + 1) * CPAD], a1) : 0;
        __syncthreads();

        // --- counting-sort scatter into LDS (edges re-read, L2-warm) ---
        for (int e = c0 + tid; e < c1; e += 256) {
            int r = rows[e];
            int b = r >> RSH;
            int pos = atomicAdd(&cur[b], 1);
            int2 cv;
            cv.x = ((r & (RPB - 1)) << 17) | cols[e];
            cv.y = __float_as_int(vals[e]);
            sorted[pos] = cv;
        }
        __syncthreads();

        // --- burst write: consecutive lanes write consecutive dsts per run.
        //     bucket of element i = smallest b with cur[b] > i (cur inclusive)
        for (int i = tid; i < cnt; i += 256) {
            int lo = 0, hi = NBMAX - 1;
            while (lo < hi) {
                int mid = (lo + hi) >> 1;
                if (cur[mid] > i) hi = mid; else lo = mid + 1;
            }
            binned[lbase[lo] + (i - pref[lo])] = sorted[i];
        }
        __syncthreads();
    }
}

// ===========================================================================
// local_csr: one 512-thread block per bucket (R9-proven). LDS 256-row hist +
// scan, write rowptr, scatter binned -> csr sorted by row (32 KB window).
// ===========================================================================
__global__ __launch_bounds__(512) void local_csr_kernel(const int* __restrict__ base,
                                                        const int2* __restrict__ binned,
                                                        int* __restrict__ rowptr,
                                                        int2* __restrict__ csr,
                                                        int n) {
    __shared__ int lh[RPB];
    __shared__ int lp[RPB];
    const int tid = threadIdx.x;
    const int b = blockIdx.x;
    const int jb = base[b], je = base[b + 1];

    for (int i = tid; i < RPB; i += 512) lh[i] = 0;
    __syncthreads();
    for (int j = jb + tid; j < je; j += 512) atomicAdd(&lh[binned[j].x >> 17], 1);
    __syncthreads();
    if (tid < RPB) lp[tid] = lh[tid];
    __syncthreads();
    for (int off = 1; off < RPB; off <<= 1) {
        int t = (tid < RPB && tid >= off) ? lp[tid - off] : 0;
        __syncthreads();
        if (tid < RPB) lp[tid] += t;
        __syncthreads();
    }
    if (tid < RPB) {
        int excl = lp[tid] - lh[tid];
        int start = jb + excl;
        lh[tid] = start;                 // becomes cursor
        int r = b * RPB + tid;
        if (r < n) rowptr[r] = start;
    }
    __syncthreads();
    for (int j = jb + tid; j < je; j += 512) {
        int2 e = binned[j];
        int rl = e.x >> 17;
        int pos = atomicAdd(&lh[rl], 1);
        int2 o; o.x = e.x & 0x1FFFF; o.y = e.y;
        csr[pos] = o;
    }
}

// ===========================================================================
// Pull v2 (R9-proven, 44us): 2 rows per wave, uint (2 bf16) gathers,
// register accumulate, 4-deep unroll.
// ===========================================================================
__global__ __launch_bounds__(256) void pull2_kernel(const int* __restrict__ rowptr,
                                                    const int2* __restrict__ csr,
                                                    const unsigned int* __restrict__ sup32,
                                                    const float* __restrict__ bias,
                                                    float* __restrict__ out, int n) {
    const int tid  = threadIdx.x;
    const int lane = tid & 63;
    const int half = lane >> 5;
    const int sub  = lane & 31;
    const int wave = blockIdx.x * 4 + (tid >> 6);
    const int nwave = gridDim.x * 4;
    const float2 b2 = reinterpret_cast<const float2*>(bias)[sub];

    for (int w = wave; 2 * w < n; w += nwave) {
        const int r = 2 * w + half;
        float ax = 0.0f, ay = 0.0f;
        if (r < n) {
            int jb = rowptr[r], je = rowptr[r + 1];
            int j = jb;
            for (; j + 3 < je; j += 4) {
                int2 e0 = csr[j], e1 = csr[j + 1], e2 = csr[j + 2], e3 = csr[j + 3];
                unsigned int u0 = sup32[(size_t)e0.x * 32 + sub];
                unsigned int u1 = sup32[(size_t)e1.x * 32 + sub];
                unsigned int u2 = sup32[(size_t)e2.x * 32 + sub];
                unsigned int u3 = sup32[(size_t)e3.x * 32 + sub];
                float v0 = __int_as_float(e0.y), v1 = __int_as_float(e1.y);
                float v2 = __int_as_float(e2.y), v3 = __int_as_float(e3.y);
                ax += v0 * __uint_as_float(u0 << 16);
                ay += v0 * __uint_as_float(u0 & 0xffff0000u);
                ax += v1 * __uint_as_float(u1 << 16);
                ay += v1 * __uint_as_float(u1 & 0xffff0000u);
                ax += v2 * __uint_as_float(u2 << 16);
                ay += v2 * __uint_as_float(u2 & 0xffff0000u);
                ax += v3 * __uint_as_float(u3 << 16);
                ay += v3 * __uint_as_float(u3 & 0xffff0000u);
            }
            for (; j < je; ++j) {
                int2 e = csr[j];
                unsigned int u = sup32[(size_t)e.x * 32 + sub];
                float v = __int_as_float(e.y);
                ax += v * __uint_as_float(u << 16);
                ay += v * __uint_as_float(u & 0xffff0000u);
            }
            float2 o; o.x = ax + b2.x; o.y = ay + b2.y;
            reinterpret_cast<float2*>(out)[(size_t)r * 32 + sub] = o;
        }
    }
}

// ===========================================================================
// Fallback (R1, verified): bias-init + atomic scatter (f32 support)
// ===========================================================================
__global__ __launch_bounds__(256) void init_kernel(const float* __restrict__ bias,
                                                   float* __restrict__ out, int total4) {
    int i = blockIdx.x * 256 + threadIdx.x;
    int stride = gridDim.x * 256;
    for (; i < total4; i += stride) {
        int base4 = (i * 4) & (D - 1);
        float4 bv;
        bv.x = bias[base4 + 0]; bv.y = bias[base4 + 1];
        bv.z = bias[base4 + 2]; bv.w = bias[base4 + 3];
        reinterpret_cast<float4*>(out)[i] = bv;
    }
}

__global__ __launch_bounds__(256) void scatter_kernel(const int* __restrict__ rows,
                                                      const int* __restrict__ cols,
                                                      const float* __restrict__ vals,
                                                      const float* __restrict__ support,
                                                      float* __restrict__ out, int ne) {
    const int wid  = blockIdx.x * 4 + (threadIdx.x >> 6);
    const int lane = threadIdx.x & 63;
    const int nw = gridDim.x * 4;
    for (int e = wid; e < ne; e += nw) {
        const int r = rows[e];
        const int c = cols[e];
        const float v = vals[e];
        unsafeAtomicAdd(&out[(size_t)r * D + lane], v * support[(size_t)c * D + lane]);
    }
}

extern "C" void kernel_launch(void* const* d_in, const int* in_sizes, int n_in,
                              void* d_out, int out_size, void* d_ws, size_t ws_size,
                              hipStream_t stream) {
    const float* x         = (const float*)d_in[0];
    const int*   edge_rows = (const int*)d_in[1];
    const int*   edge_cols = (const int*)d_in[2];
    const float* edge_vals = (const float*)d_in[3];
    const float* w_own     = (const float*)d_in[4];
    const float* w_nbr     = (const float*)d_in[5];
    const float* w_temp    = (const float*)d_in[6];
    const float* bias      = (const float*)d_in[7];

    float* out = (float*)d_out;
    const int n_nodes = in_sizes[0] / D;
    const int n_edges = in_sizes[1];
    const int nb = (n_nodes + RPB - 1) / RPB;

    // ---- workspace layout ----
    char* ws = (char*)d_ws;
    size_t off = 0;
    auto take = [&](size_t bytes) -> char* {
        char* p = ws + off;
        off = (off + bytes + 15) & ~(size_t)15;
        return p;
    };
    __hip_bfloat16* support = (__hip_bfloat16*)take((size_t)n_nodes * D * sizeof(__hip_bfloat16));
    int2* binned = (int2*)take((size_t)n_edges * sizeof(int2));
    int2* csr    = (int2*)take((size_t)n_edges * sizeof(int2));
    int*  rowptr = (int*) take((size_t)(n_nodes + 1) * sizeof(int));
    int*  gcnt   = (int*) take((size_t)nb * CPAD * sizeof(int));
    int*  base   = (int*) take((size_t)(nb + 1) * sizeof(int));
    int*  cursor = (int*) take((size_t)nb * CPAD * sizeof(int));
    const bool full_fits = (off <= ws_size) && (nb <= NBMAX) && (n_nodes <= (1 << 17));

    if (full_fits) {
        gemm_kernel<<<1024, 256, 0, stream>>>(x, w_own, w_nbr, w_temp, support, n_nodes);
        hipMemsetAsync(gcnt, 0, (size_t)nb * CPAD * sizeof(int), stream);
        bucket_hist_kernel<<<1024, 256, 0, stream>>>(edge_rows, n_edges, gcnt, nb);
        bucket_scan_kernel<<<1, 256, 0, stream>>>(gcnt, nb, base, cursor);
        bin_sort_scatter_kernel<<<512, 256, 0, stream>>>(edge_rows, edge_cols, edge_vals,
                                                         n_edges, cursor, nb, binned);
        local_csr_kernel<<<nb, 512, 0, stream>>>(base, binned, rowptr, csr, n_nodes);
        hipMemcpyAsync(rowptr + n_nodes, base + nb, sizeof(int),
                       hipMemcpyDeviceToDevice, stream);
        pull2_kernel<<<2048, 256, 0, stream>>>(rowptr, csr, (const unsigned int*)support,
                                               bias, out, n_nodes);
    } else {
        // R1 fallback: f32 support + atomic scatter
        float* support_f = (float*)d_ws;
        gemm_f32_kernel<<<1024, 256, 0, stream>>>(x, w_own, w_nbr, w_temp, support_f, n_nodes);
        int total4 = (n_nodes * D) / 4;
        int blocks = (total4 + 255) / 256; if (blocks > 2048) blocks = 2048;
        init_kernel<<<blocks, 256, 0, stream>>>(bias, out, total4);
        scatter_kernel<<<2048, 256, 0, stream>>>(edge_rows, edge_cols, edge_vals,
                                                 support_f, out, n_edges);
    }
}

// Round 13
// 145.775 us; speedup vs baseline: 1.2560x; 1.0417x over previous
//
#include <hip/hip_runtime.h>
#include <hip/hip_bf16.h>

#define D 64
#define RPB 256          // rows per bucket (row_local 8 bits)
#define RSH 8            // log2(RPB)
#define NBMAX 1024       // max buckets; needs n_nodes <= 131072 (17-bit col)
#define CPAD 16          // ints per padded counter (64 B line)

// ===========================================================================
// support = x @ (W0+W1+W2), stored as bf16
// ===========================================================================
__global__ __launch_bounds__(256) void gemm_kernel(const float* __restrict__ x,
                                                   const float* __restrict__ w0,
                                                   const float* __restrict__ w1,
                                                   const float* __restrict__ w2,
                                                   __hip_bfloat16* __restrict__ support,
                                                   int n) {
    __shared__ float Ws[D * D];
    __shared__ float xs[4][D];

    for (int i = threadIdx.x; i < D * D; i += 256)
        Ws[i] = w0[i] + w1[i] + w2[i];
    __syncthreads();

    const int wid  = threadIdx.x >> 6;
    const int lane = threadIdx.x & 63;
    int row = blockIdx.x * 4 + wid;
    const int nw = gridDim.x * 4;

    for (; row < n; row += nw) {
        xs[wid][lane] = x[(size_t)row * D + lane];
        float acc = 0.0f;
#pragma unroll
        for (int k = 0; k < D; ++k) {
            acc += xs[wid][k] * Ws[k * D + lane];
        }
        support[(size_t)row * D + lane] = __float2bfloat16(acc);
    }
}

// f32-support variant for the fallback path
__global__ __launch_bounds__(256) void gemm_f32_kernel(const float* __restrict__ x,
                                                       const float* __restrict__ w0,
                                                       const float* __restrict__ w1,
                                                       const float* __restrict__ w2,
                                                       float* __restrict__ support,
                                                       int n) {
    __shared__ float Ws[D * D];
    __shared__ float xs[4][D];
    for (int i = threadIdx.x; i < D * D; i += 256)
        Ws[i] = w0[i] + w1[i] + w2[i];
    __syncthreads();
    const int wid  = threadIdx.x >> 6;
    const int lane = threadIdx.x & 63;
    int row = blockIdx.x * 4 + wid;
    const int nw = gridDim.x * 4;
    for (; row < n; row += nw) {
        xs[wid][lane] = x[(size_t)row * D + lane];
        float acc = 0.0f;
#pragma unroll
        for (int k = 0; k < D; ++k) acc += xs[wid][k] * Ws[k * D + lane];
        support[(size_t)row * D + lane] = acc;
    }
}

// ===========================================================================
// Binning (R9-proven): hist -> scan -> partition scatter, padded counters
// ===========================================================================
__global__ __launch_bounds__(256) void bucket_hist_kernel(const int* __restrict__ rows,
                                                          int ne, int* __restrict__ gcnt,
                                                          int nb) {
    __shared__ int lcnt[NBMAX];
    for (int i = threadIdx.x; i < nb; i += 256) lcnt[i] = 0;
    __syncthreads();
    int i = blockIdx.x * 256 + threadIdx.x;
    int stride = gridDim.x * 256;
    for (; i < ne; i += stride) atomicAdd(&lcnt[rows[i] >> RSH], 1);
    __syncthreads();
    for (int b = threadIdx.x; b < nb; b += 256) {
        int c = lcnt[b];
        if (c) atomicAdd(&gcnt[b * CPAD], c);
    }
}

__global__ __launch_bounds__(256) void bucket_scan_kernel(const int* __restrict__ gcnt,
                                                          int nb,
                                                          int* __restrict__ base,
                                                          int* __restrict__ cursor) {
    __shared__ int ts[256];
    const int tid = threadIdx.x;
    int b0 = tid * 4;
    int v[4]; int tsum = 0;
#pragma unroll
    for (int j = 0; j < 4; ++j) {
        int idx = b0 + j;
        v[j] = (idx < nb) ? gcnt[idx * CPAD] : 0;
        tsum += v[j];
    }
    ts[tid] = tsum;
    __syncthreads();
    for (int off = 1; off < 256; off <<= 1) {
        int t = (tid >= off) ? ts[tid - off] : 0;
        __syncthreads();
        ts[tid] += t;
        __syncthreads();
    }
    int excl = ts[tid] - tsum;
#pragma unroll
    for (int j = 0; j < 4; ++j) {
        int idx = b0 + j;
        if (idx < nb) { base[idx] = excl; cursor[idx * CPAD] = excl; }
        excl += v[j];
    }
    if (tid == 255) base[nb] = excl;
}

__global__ __launch_bounds__(256) void bin_scatter_kernel(const int* __restrict__ rows,
                                                          const int* __restrict__ cols,
                                                          const float* __restrict__ vals,
                                                          int ne,
                                                          int* __restrict__ cursor,
                                                          int nb,
                                                          int2* __restrict__ binned) {
    __shared__ int lcnt[NBMAX];
    __shared__ int lbase[NBMAX];
    const int tid = threadIdx.x;
    const int ce = (ne + gridDim.x - 1) / gridDim.x;
    const int e0 = blockIdx.x * ce;
    const int e1 = min(ne, e0 + ce);

    for (int i = tid; i < nb; i += 256) lcnt[i] = 0;
    __syncthreads();
    for (int e = e0 + tid; e < e1; e += 256) atomicAdd(&lcnt[rows[e] >> RSH], 1);
    __syncthreads();
    for (int b = tid; b < nb; b += 256) {
        int c = lcnt[b];
        lbase[b] = c ? atomicAdd(&cursor[b * CPAD], c) : 0;
    }
    __syncthreads();
    for (int i = tid; i < nb; i += 256) lcnt[i] = 0;   // reuse as local cursor
    __syncthreads();
    for (int e = e0 + tid; e < e1; e += 256) {
        int r = rows[e];
        int b = r >> RSH;
        int loc = atomicAdd(&lcnt[b], 1);
        int2 cv;
        cv.x = ((r & (RPB - 1)) << 17) | cols[e];
        cv.y = __float_as_int(vals[e]);
        binned[lbase[b] + loc] = cv;
    }
}

// ===========================================================================
// local_csr: one 1024-thread block per bucket. LDS 256-row hist + scan, write
// rowptr, scatter binned -> csr sorted by row (contiguous ~32 KB window).
// ===========================================================================
__global__ __launch_bounds__(1024) void local_csr_kernel(const int* __restrict__ base,
                                                         const int2* __restrict__ binned,
                                                         int* __restrict__ rowptr,
                                                         int2* __restrict__ csr,
                                                         int n) {
    __shared__ int lh[RPB];
    __shared__ int lp[RPB];
    const int tid = threadIdx.x;
    const int b = blockIdx.x;
    const int jb = base[b], je = base[b + 1];

    for (int i = tid; i < RPB; i += 1024) lh[i] = 0;
    __syncthreads();
    for (int j = jb + tid; j < je; j += 1024) atomicAdd(&lh[binned[j].x >> 17], 1);
    __syncthreads();
    if (tid < RPB) lp[tid] = lh[tid];
    __syncthreads();
    for (int off = 1; off < RPB; off <<= 1) {
        int t = (tid < RPB && tid >= off) ? lp[tid - off] : 0;
        __syncthreads();
        if (tid < RPB) lp[tid] += t;
        __syncthreads();
    }
    if (tid < RPB) {
        int excl = lp[tid] - lh[tid];
        int start = jb + excl;
        lh[tid] = start;                 // becomes cursor
        int r = b * RPB + tid;
        if (r < n) rowptr[r] = start;
    }
    __syncthreads();
    for (int j = jb + tid; j < je; j += 1024) {
        int2 e = binned[j];
        int rl = e.x >> 17;
        int pos = atomicAdd(&lh[rl], 1);
        int2 o; o.x = e.x & 0x1FFFF; o.y = e.y;
        csr[pos] = o;
    }
}

// ===========================================================================
// Pull v3: 2 rows per wave, uint (2 bf16) gathers, register accumulate,
// 8-deep unroll (was 4) — doubles outstanding gathers per half-wave to
// attack the measured gather-latency bound (VALUBusy 33%, occ 65%).
// ===========================================================================
__global__ __launch_bounds__(256) void pull2_kernel(const int* __restrict__ rowptr,
                                                    const int2* __restrict__ csr,
                                                    const unsigned int* __restrict__ sup32,
                                                    const float* __restrict__ bias,
                                                    float* __restrict__ out, int n) {
    const int tid  = threadIdx.x;
    const int lane = tid & 63;
    const int half = lane >> 5;
    const int sub  = lane & 31;
    const int wave = blockIdx.x * 4 + (tid >> 6);
    const int nwave = gridDim.x * 4;
    const float2 b2 = reinterpret_cast<const float2*>(bias)[sub];

    for (int w = wave; 2 * w < n; w += nwave) {
        const int r = 2 * w + half;
        float ax = 0.0f, ay = 0.0f;
        if (r < n) {
            const int jb = rowptr[r], je = rowptr[r + 1];
            int j = jb;
            for (; j + 7 < je; j += 8) {
                int2 e[8];
#pragma unroll
                for (int u = 0; u < 8; ++u) e[u] = csr[j + u];
                unsigned int g[8];
#pragma unroll
                for (int u = 0; u < 8; ++u)
                    g[u] = sup32[(size_t)e[u].x * 32 + sub];
#pragma unroll
                for (int u = 0; u < 8; ++u) {
                    float v = __int_as_float(e[u].y);
                    ax += v * __uint_as_float(g[u] << 16);
                    ay += v * __uint_as_float(g[u] & 0xffff0000u);
                }
            }
            for (; j + 1 < je; j += 2) {
                int2 e0 = csr[j], e1 = csr[j + 1];
                unsigned int u0 = sup32[(size_t)e0.x * 32 + sub];
                unsigned int u1 = sup32[(size_t)e1.x * 32 + sub];
                float v0 = __int_as_float(e0.y), v1 = __int_as_float(e1.y);
                ax += v0 * __uint_as_float(u0 << 16);
                ay += v0 * __uint_as_float(u0 & 0xffff0000u);
                ax += v1 * __uint_as_float(u1 << 16);
                ay += v1 * __uint_as_float(u1 & 0xffff0000u);
            }
            if (j < je) {
                int2 e = csr[j];
                unsigned int u = sup32[(size_t)e.x * 32 + sub];
                float v = __int_as_float(e.y);
                ax += v * __uint_as_float(u << 16);
                ay += v * __uint_as_float(u & 0xffff0000u);
            }
            float2 o; o.x = ax + b2.x; o.y = ay + b2.y;
            reinterpret_cast<float2*>(out)[(size_t)r * 32 + sub] = o;
        }
    }
}

// ===========================================================================
// Fallback (R1, verified): bias-init + atomic scatter (f32 support)
// ===========================================================================
__global__ __launch_bounds__(256) void init_kernel(const float* __restrict__ bias,
                                                   float* __restrict__ out, int total4) {
    int i = blockIdx.x * 256 + threadIdx.x;
    int stride = gridDim.x * 256;
    for (; i < total4; i += stride) {
        int base4 = (i * 4) & (D - 1);
        float4 bv;
        bv.x = bias[base4 + 0]; bv.y = bias[base4 + 1];
        bv.z = bias[base4 + 2]; bv.w = bias[base4 + 3];
        reinterpret_cast<float4*>(out)[i] = bv;
    }
}

__global__ __launch_bounds__(256) void scatter_kernel(const int* __restrict__ rows,
                                                      const int* __restrict__ cols,
                                                      const float* __restrict__ vals,
                                                      const float* __restrict__ support,
                                                      float* __restrict__ out, int ne) {
    const int wid  = blockIdx.x * 4 + (threadIdx.x >> 6);
    const int lane = threadIdx.x & 63;
    const int nw = gridDim.x * 4;
    for (int e = wid; e < ne; e += nw) {
        const int r = rows[e];
        const int c = cols[e];
        const float v = vals[e];
        unsafeAtomicAdd(&out[(size_t)r * D + lane], v * support[(size_t)c * D + lane]);
    }
}

extern "C" void kernel_launch(void* const* d_in, const int* in_sizes, int n_in,
                              void* d_out, int out_size, void* d_ws, size_t ws_size,
                              hipStream_t stream) {
    const float* x         = (const float*)d_in[0];
    const int*   edge_rows = (const int*)d_in[1];
    const int*   edge_cols = (const int*)d_in[2];
    const float* edge_vals = (const float*)d_in[3];
    const float* w_own     = (const float*)d_in[4];
    const float* w_nbr     = (const float*)d_in[5];
    const float* w_temp    = (const float*)d_in[6];
    const float* bias      = (const float*)d_in[7];

    float* out = (float*)d_out;
    const int n_nodes = in_sizes[0] / D;
    const int n_edges = in_sizes[1];
    const int nb = (n_nodes + RPB - 1) / RPB;

    // ---- workspace layout ----
    char* ws = (char*)d_ws;
    size_t off = 0;
    auto take = [&](size_t bytes) -> char* {
        char* p = ws + off;
        off = (off + bytes + 15) & ~(size_t)15;
        return p;
    };
    __hip_bfloat16* support = (__hip_bfloat16*)take((size_t)n_nodes * D * sizeof(__hip_bfloat16));
    int2* binned = (int2*)take((size_t)n_edges * sizeof(int2));
    int2* csr    = (int2*)take((size_t)n_edges * sizeof(int2));
    int*  rowptr = (int*) take((size_t)(n_nodes + 1) * sizeof(int));
    int*  gcnt   = (int*) take((size_t)nb * CPAD * sizeof(int));
    int*  base   = (int*) take((size_t)(nb + 1) * sizeof(int));
    int*  cursor = (int*) take((size_t)nb * CPAD * sizeof(int));
    const bool full_fits = (off <= ws_size) && (nb <= NBMAX) && (n_nodes <= (1 << 17));

    if (full_fits) {
        gemm_kernel<<<1024, 256, 0, stream>>>(x, w_own, w_nbr, w_temp, support, n_nodes);
        hipMemsetAsync(gcnt, 0, (size_t)nb * CPAD * sizeof(int), stream);
        bucket_hist_kernel<<<1024, 256, 0, stream>>>(edge_rows, n_edges, gcnt, nb);
        bucket_scan_kernel<<<1, 256, 0, stream>>>(gcnt, nb, base, cursor);
        bin_scatter_kernel<<<512, 256, 0, stream>>>(edge_rows, edge_cols, edge_vals,
                                                    n_edges, cursor, nb, binned);
        local_csr_kernel<<<nb, 1024, 0, stream>>>(base, binned, rowptr, csr, n_nodes);
        hipMemcpyAsync(rowptr + n_nodes, base + nb, sizeof(int),
                       hipMemcpyDeviceToDevice, stream);
        pull2_kernel<<<2048, 256, 0, stream>>>(rowptr, csr, (const unsigned int*)support,
                                               bias, out, n_nodes);
    } else {
        // R1 fallback: f32 support + atomic scatter
        float* support_f = (float*)d_ws;
        gemm_f32_kernel<<<1024, 256, 0, stream>>>(x, w_own, w_nbr, w_temp, support_f, n_nodes);
        int total4 = (n_nodes * D) / 4;
        int blocks = (total4 + 255) / 256; if (blocks > 2048) blocks = 2048;
        init_kernel<<<blocks, 256, 0, stream>>>(bias, out, total4);
        scatter_kernel<<<2048, 256, 0, stream>>>(edge_rows, edge_cols, edge_vals,
                                                 support_f, out, n_edges);
    }
}

// Round 14
// 139.699 us; speedup vs baseline: 1.3106x; 1.0435x over previous
//
#include <hip/hip_runtime.h>
#include <hip/hip_bf16.h>

#define D 64
#define RPB 1024         // rows per bin bucket (rl fits in 10 bits; col 17 bits -> 27)
#define RSH 10           // log2(RPB)
#define NBB 128          // max buckets (n_nodes <= 131072)
#define CPAD 16          // ints per padded counter (64 B line)

// ===========================================================================
// support = x @ (W0+W1+W2), stored as bf16
// ===========================================================================
__global__ __launch_bounds__(256) void gemm_kernel(const float* __restrict__ x,
                                                   const float* __restrict__ w0,
                                                   const float* __restrict__ w1,
                                                   const float* __restrict__ w2,
                                                   __hip_bfloat16* __restrict__ support,
                                                   int n) {
    __shared__ float Ws[D * D];
    __shared__ float xs[4][D];

    for (int i = threadIdx.x; i < D * D; i += 256)
        Ws[i] = w0[i] + w1[i] + w2[i];
    __syncthreads();

    const int wid  = threadIdx.x >> 6;
    const int lane = threadIdx.x & 63;
    int row = blockIdx.x * 4 + wid;
    const int nw = gridDim.x * 4;

    for (; row < n; row += nw) {
        xs[wid][lane] = x[(size_t)row * D + lane];
        float acc = 0.0f;
#pragma unroll
        for (int k = 0; k < D; ++k) {
            acc += xs[wid][k] * Ws[k * D + lane];
        }
        support[(size_t)row * D + lane] = __float2bfloat16(acc);
    }
}

// f32-support variant for the fallback path
__global__ __launch_bounds__(256) void gemm_f32_kernel(const float* __restrict__ x,
                                                       const float* __restrict__ w0,
                                                       const float* __restrict__ w1,
                                                       const float* __restrict__ w2,
                                                       float* __restrict__ support,
                                                       int n) {
    __shared__ float Ws[D * D];
    __shared__ float xs[4][D];
    for (int i = threadIdx.x; i < D * D; i += 256)
        Ws[i] = w0[i] + w1[i] + w2[i];
    __syncthreads();
    const int wid  = threadIdx.x >> 6;
    const int lane = threadIdx.x & 63;
    int row = blockIdx.x * 4 + wid;
    const int nw = gridDim.x * 4;
    for (; row < n; row += nw) {
        xs[wid][lane] = x[(size_t)row * D + lane];
        float acc = 0.0f;
#pragma unroll
        for (int k = 0; k < D; ++k) acc += xs[wid][k] * Ws[k * D + lane];
        support[(size_t)row * D + lane] = acc;
    }
}

// ===========================================================================
// Binning: hist (98 coarse buckets) -> scan -> partition scatter.
// Coarse buckets -> ~32-edge (256 B) runs -> low partial-line writeback.
// ===========================================================================
__global__ __launch_bounds__(256) void bucket_hist_kernel(const int* __restrict__ rows,
                                                          int ne, int* __restrict__ gcnt,
                                                          int nb) {
    __shared__ int lcnt[NBB];
    for (int i = threadIdx.x; i < nb; i += 256) lcnt[i] = 0;
    __syncthreads();
    int i = blockIdx.x * 256 + threadIdx.x;
    int stride = gridDim.x * 256;
    for (; i < ne; i += stride) atomicAdd(&lcnt[rows[i] >> RSH], 1);
    __syncthreads();
    for (int b = threadIdx.x; b < nb; b += 256) {
        int c = lcnt[b];
        if (c) atomicAdd(&gcnt[b * CPAD], c);
    }
}

__global__ __launch_bounds__(256) void bucket_scan_kernel(const int* __restrict__ gcnt,
                                                          int nb,
                                                          int* __restrict__ base,
                                                          int* __restrict__ cursor) {
    __shared__ int ts[256];
    const int tid = threadIdx.x;
    int v = (tid < nb) ? gcnt[tid * CPAD] : 0;
    ts[tid] = v;
    __syncthreads();
    for (int off = 1; off < 256; off <<= 1) {
        int t = (tid >= off) ? ts[tid - off] : 0;
        __syncthreads();
        ts[tid] += t;
        __syncthreads();
    }
    int excl = ts[tid] - v;
    if (tid < nb) { base[tid] = excl; cursor[tid * CPAD] = excl; }
    if (tid == 255) base[nb] = ts[255];
}

__global__ __launch_bounds__(256) void bin_scatter_kernel(const int* __restrict__ rows,
                                                          const int* __restrict__ cols,
                                                          const float* __restrict__ vals,
                                                          int ne,
                                                          int* __restrict__ cursor,
                                                          int nb,
                                                          int2* __restrict__ binned) {
    __shared__ int lcnt[NBB];
    __shared__ int lbase[NBB];
    const int tid = threadIdx.x;
    const int ce = (ne + gridDim.x - 1) / gridDim.x;
    const int e0 = blockIdx.x * ce;
    const int e1 = min(ne, e0 + ce);

    for (int i = tid; i < nb; i += 256) lcnt[i] = 0;
    __syncthreads();
    for (int e = e0 + tid; e < e1; e += 256) atomicAdd(&lcnt[rows[e] >> RSH], 1);
    __syncthreads();
    for (int b = tid; b < nb; b += 256) {
        int c = lcnt[b];
        lbase[b] = c ? atomicAdd(&cursor[b * CPAD], c) : 0;
    }
    __syncthreads();
    for (int i = tid; i < nb; i += 256) lcnt[i] = 0;   // reuse as local cursor
    __syncthreads();
    for (int e = e0 + tid; e < e1; e += 256) {
        int r = rows[e];
        int b = r >> RSH;
        int loc = atomicAdd(&lcnt[b], 1);
        int2 cv;
        cv.x = ((r & (RPB - 1)) << 17) | cols[e];
        cv.y = __float_as_int(vals[e]);
        binned[lbase[b] + loc] = cv;
    }
}

// ===========================================================================
// local_csr: grid = nb*4 blocks of 512 threads. Block (b,q): full 1024-bin
// hist of bucket b's segment, in-block scan, rowptr for its 2 bins/thread,
// then scatter ONLY quarter q's rows (256) into its contiguous ~32 KB window
// (streaming full-line writes, L2-resident).
// ===========================================================================
__global__ __launch_bounds__(512) void local_csr_kernel(const int* __restrict__ base,
                                                        const int2* __restrict__ binned,
                                                        int* __restrict__ rowptr,
                                                        int2* __restrict__ csr,
                                                        int n) {
    __shared__ int lh[RPB];     // hist -> cursor (4 KB)
    __shared__ int ts[512];
    const int tid = threadIdx.x;
    const int b = blockIdx.x >> 2;
    const int q = blockIdx.x & 3;
    const int jb = base[b], je = base[b + 1];

    lh[2 * tid] = 0; lh[2 * tid + 1] = 0;
    __syncthreads();
    for (int j = jb + tid; j < je; j += 512)
        atomicAdd(&lh[binned[j].x >> 17], 1);
    __syncthreads();

    const int v0 = lh[2 * tid], v1 = lh[2 * tid + 1];
    const int tsum = v0 + v1;
    ts[tid] = tsum;
    __syncthreads();
    for (int off = 1; off < 512; off <<= 1) {
        int t = (tid >= off) ? ts[tid - off] : 0;
        __syncthreads();
        ts[tid] += t;
        __syncthreads();
    }
    int excl = ts[tid] - tsum + jb;
    __syncthreads();           // everyone done reading lh as hist

    const int r0 = b * RPB + 2 * tid;
    lh[2 * tid] = excl;
    if (r0 < n) rowptr[r0] = excl;
    lh[2 * tid + 1] = excl + v0;
    if (r0 + 1 < n) rowptr[r0 + 1] = excl + v0;
    __syncthreads();

    for (int j = jb + tid; j < je; j += 512) {
        int2 e = binned[j];
        int rl = e.x >> 17;
        if ((rl >> 8) == q) {
            int pos = atomicAdd(&lh[rl], 1);
            int2 o; o.x = e.x & 0x1FFFF; o.y = e.y;
            csr[pos] = o;
        }
    }
}

// ===========================================================================
// Pull (R13): 2 rows per wave, uint (2 bf16) gathers, register accumulate,
// 8-deep unroll.
// ===========================================================================
__global__ __launch_bounds__(256) void pull2_kernel(const int* __restrict__ rowptr,
                                                    const int2* __restrict__ csr,
                                                    const unsigned int* __restrict__ sup32,
                                                    const float* __restrict__ bias,
                                                    float* __restrict__ out, int n) {
    const int tid  = threadIdx.x;
    const int lane = tid & 63;
    const int half = lane >> 5;
    const int sub  = lane & 31;
    const int wave = blockIdx.x * 4 + (tid >> 6);
    const int nwave = gridDim.x * 4;
    const float2 b2 = reinterpret_cast<const float2*>(bias)[sub];

    for (int w = wave; 2 * w < n; w += nwave) {
        const int r = 2 * w + half;
        float ax = 0.0f, ay = 0.0f;
        if (r < n) {
            const int jb = rowptr[r], je = rowptr[r + 1];
            int j = jb;
            for (; j + 7 < je; j += 8) {
                int2 e[8];
#pragma unroll
                for (int u = 0; u < 8; ++u) e[u] = csr[j + u];
                unsigned int g[8];
#pragma unroll
                for (int u = 0; u < 8; ++u)
                    g[u] = sup32[(size_t)e[u].x * 32 + sub];
#pragma unroll
                for (int u = 0; u < 8; ++u) {
                    float v = __int_as_float(e[u].y);
                    ax += v * __uint_as_float(g[u] << 16);
                    ay += v * __uint_as_float(g[u] & 0xffff0000u);
                }
            }
            for (; j + 1 < je; j += 2) {
                int2 e0 = csr[j], e1 = csr[j + 1];
                unsigned int u0 = sup32[(size_t)e0.x * 32 + sub];
                unsigned int u1 = sup32[(size_t)e1.x * 32 + sub];
                float v0 = __int_as_float(e0.y), v1 = __int_as_float(e1.y);
                ax += v0 * __uint_as_float(u0 << 16);
                ay += v0 * __uint_as_float(u0 & 0xffff0000u);
                ax += v1 * __uint_as_float(u1 << 16);
                ay += v1 * __uint_as_float(u1 & 0xffff0000u);
            }
            if (j < je) {
                int2 e = csr[j];
                unsigned int u = sup32[(size_t)e.x * 32 + sub];
                float v = __int_as_float(e.y);
                ax += v * __uint_as_float(u << 16);
                ay += v * __uint_as_float(u & 0xffff0000u);
            }
            float2 o; o.x = ax + b2.x; o.y = ay + b2.y;
            reinterpret_cast<float2*>(out)[(size_t)r * 32 + sub] = o;
        }
    }
}

// ===========================================================================
// Fallback (R1, verified): bias-init + atomic scatter (f32 support)
// ===========================================================================
__global__ __launch_bounds__(256) void init_kernel(const float* __restrict__ bias,
                                                   float* __restrict__ out, int total4) {
    int i = blockIdx.x * 256 + threadIdx.x;
    int stride = gridDim.x * 256;
    for (; i < total4; i += stride) {
        int base4 = (i * 4) & (D - 1);
        float4 bv;
        bv.x = bias[base4 + 0]; bv.y = bias[base4 + 1];
        bv.z = bias[base4 + 2]; bv.w = bias[base4 + 3];
        reinterpret_cast<float4*>(out)[i] = bv;
    }
}

__global__ __launch_bounds__(256) void scatter_kernel(const int* __restrict__ rows,
                                                      const int* __restrict__ cols,
                                                      const float* __restrict__ vals,
                                                      const float* __restrict__ support,
                                                      float* __restrict__ out, int ne) {
    const int wid  = blockIdx.x * 4 + (threadIdx.x >> 6);
    const int lane = threadIdx.x & 63;
    const int nw = gridDim.x * 4;
    for (int e = wid; e < ne; e += nw) {
        const int r = rows[e];
        const int c = cols[e];
        const float v = vals[e];
        unsafeAtomicAdd(&out[(size_t)r * D + lane], v * support[(size_t)c * D + lane]);
    }
}

extern "C" void kernel_launch(void* const* d_in, const int* in_sizes, int n_in,
                              void* d_out, int out_size, void* d_ws, size_t ws_size,
                              hipStream_t stream) {
    const float* x         = (const float*)d_in[0];
    const int*   edge_rows = (const int*)d_in[1];
    const int*   edge_cols = (const int*)d_in[2];
    const float* edge_vals = (const float*)d_in[3];
    const float* w_own     = (const float*)d_in[4];
    const float* w_nbr     = (const float*)d_in[5];
    const float* w_temp    = (const float*)d_in[6];
    const float* bias      = (const float*)d_in[7];

    float* out = (float*)d_out;
    const int n_nodes = in_sizes[0] / D;
    const int n_edges = in_sizes[1];
    const int nb = (n_nodes + RPB - 1) / RPB;

    // ---- workspace layout ----
    char* ws = (char*)d_ws;
    size_t off = 0;
    auto take = [&](size_t bytes) -> char* {
        char* p = ws + off;
        off = (off + bytes + 15) & ~(size_t)15;
        return p;
    };
    __hip_bfloat16* support = (__hip_bfloat16*)take((size_t)n_nodes * D * sizeof(__hip_bfloat16));
    int2* binned = (int2*)take((size_t)n_edges * sizeof(int2));
    int2* csr    = (int2*)take((size_t)n_edges * sizeof(int2));
    int*  rowptr = (int*) take((size_t)(n_nodes + 1) * sizeof(int));
    int*  gcnt   = (int*) take((size_t)nb * CPAD * sizeof(int));
    int*  base   = (int*) take((size_t)(nb + 1) * sizeof(int));
    int*  cursor = (int*) take((size_t)nb * CPAD * sizeof(int));
    const bool full_fits = (off <= ws_size) && (nb <= NBB) && (n_nodes <= (1 << 17));

    if (full_fits) {
        gemm_kernel<<<1024, 256, 0, stream>>>(x, w_own, w_nbr, w_temp, support, n_nodes);
        hipMemsetAsync(gcnt, 0, (size_t)nb * CPAD * sizeof(int), stream);
        bucket_hist_kernel<<<512, 256, 0, stream>>>(edge_rows, n_edges, gcnt, nb);
        bucket_scan_kernel<<<1, 256, 0, stream>>>(gcnt, nb, base, cursor);
        bin_scatter_kernel<<<512, 256, 0, stream>>>(edge_rows, edge_cols, edge_vals,
                                                    n_edges, cursor, nb, binned);
        local_csr_kernel<<<nb * 4, 512, 0, stream>>>(base, binned, rowptr, csr, n_nodes);
        hipMemcpyAsync(rowptr + n_nodes, base + nb, sizeof(int),
                       hipMemcpyDeviceToDevice, stream);
        pull2_kernel<<<2048, 256, 0, stream>>>(rowptr, csr, (const unsigned int*)support,
                                               bias, out, n_nodes);
    } else {
        // R1 fallback: f32 support + atomic scatter
        float* support_f = (float*)d_ws;
        gemm_f32_kernel<<<1024, 256, 0, stream>>>(x, w_own, w_nbr, w_temp, support_f, n_nodes);
        int total4 = (n_nodes * D) / 4;
        int blocks = (total4 + 255) / 256; if (blocks > 2048) blocks = 2048;
        init_kernel<<<blocks, 256, 0, stream>>>(bias, out, total4);
        scatter_kernel<<<2048, 256, 0, stream>>>(edge_rows, edge_cols, edge_vals,
                                                 support_f, out, n_edges);
    }
}

// Round 15
// 138.662 us; speedup vs baseline: 1.3204x; 1.0075x over previous
//
#include <hip/hip_runtime.h>
#include <hip/hip_bf16.h>

#define D 64
#define RPB 1024         // rows per bin bucket (rl fits in 10 bits; col 17 bits -> 27)
#define RSH 10           // log2(RPB)
#define NBB 128          // max buckets (n_nodes <= 131072)
#define CPAD 16          // ints per padded counter (64 B line)

// ===========================================================================
// support = x @ (W0+W1+W2), stored as bf16
// ===========================================================================
__global__ __launch_bounds__(256) void gemm_kernel(const float* __restrict__ x,
                                                   const float* __restrict__ w0,
                                                   const float* __restrict__ w1,
                                                   const float* __restrict__ w2,
                                                   __hip_bfloat16* __restrict__ support,
                                                   int n) {
    __shared__ float Ws[D * D];
    __shared__ float xs[4][D];

    for (int i = threadIdx.x; i < D * D; i += 256)
        Ws[i] = w0[i] + w1[i] + w2[i];
    __syncthreads();

    const int wid  = threadIdx.x >> 6;
    const int lane = threadIdx.x & 63;
    int row = blockIdx.x * 4 + wid;
    const int nw = gridDim.x * 4;

    for (; row < n; row += nw) {
        xs[wid][lane] = x[(size_t)row * D + lane];
        float acc = 0.0f;
#pragma unroll
        for (int k = 0; k < D; ++k) {
            acc += xs[wid][k] * Ws[k * D + lane];
        }
        support[(size_t)row * D + lane] = __float2bfloat16(acc);
    }
}

// f32-support variant for the fallback path
__global__ __launch_bounds__(256) void gemm_f32_kernel(const float* __restrict__ x,
                                                       const float* __restrict__ w0,
                                                       const float* __restrict__ w1,
                                                       const float* __restrict__ w2,
                                                       float* __restrict__ support,
                                                       int n) {
    __shared__ float Ws[D * D];
    __shared__ float xs[4][D];
    for (int i = threadIdx.x; i < D * D; i += 256)
        Ws[i] = w0[i] + w1[i] + w2[i];
    __syncthreads();
    const int wid  = threadIdx.x >> 6;
    const int lane = threadIdx.x & 63;
    int row = blockIdx.x * 4 + wid;
    const int nw = gridDim.x * 4;
    for (; row < n; row += nw) {
        xs[wid][lane] = x[(size_t)row * D + lane];
        float acc = 0.0f;
#pragma unroll
        for (int k = 0; k < D; ++k) acc += xs[wid][k] * Ws[k * D + lane];
        support[(size_t)row * D + lane] = acc;
    }
}

// ===========================================================================
// Binning: zero -> hist (98 coarse buckets) -> scan -> partition scatter.
// Coarse buckets -> ~32-edge (256 B) runs -> low partial-line writeback.
// NOTE: hipMemsetAsync costs ~41us of GPU time (rocclr fill kernel, measured
// R14) — use a tiny zero kernel instead.
// ===========================================================================
__global__ __launch_bounds__(256) void zero_kernel(int* __restrict__ p, int n) {
    int i = blockIdx.x * 256 + threadIdx.x;
    int stride = gridDim.x * 256;
    for (; i < n; i += stride) p[i] = 0;
}

__global__ __launch_bounds__(256) void bucket_hist_kernel(const int* __restrict__ rows,
                                                          int ne, int* __restrict__ gcnt,
                                                          int nb) {
    __shared__ int lcnt[NBB];
    for (int i = threadIdx.x; i < nb; i += 256) lcnt[i] = 0;
    __syncthreads();
    int i = blockIdx.x * 256 + threadIdx.x;
    int stride = gridDim.x * 256;
    for (; i < ne; i += stride) atomicAdd(&lcnt[rows[i] >> RSH], 1);
    __syncthreads();
    for (int b = threadIdx.x; b < nb; b += 256) {
        int c = lcnt[b];
        if (c) atomicAdd(&gcnt[b * CPAD], c);
    }
}

// 1 block: exclusive scan -> base[nb+1], cursor copy; also rowptr[n] sentinel
// (folds away the hipMemcpyAsync dispatch).
__global__ __launch_bounds__(256) void bucket_scan_kernel(const int* __restrict__ gcnt,
                                                          int nb,
                                                          int* __restrict__ base,
                                                          int* __restrict__ cursor,
                                                          int* __restrict__ rowptr,
                                                          int n) {
    __shared__ int ts[256];
    const int tid = threadIdx.x;
    int v = (tid < nb) ? gcnt[tid * CPAD] : 0;
    ts[tid] = v;
    __syncthreads();
    for (int off = 1; off < 256; off <<= 1) {
        int t = (tid >= off) ? ts[tid - off] : 0;
        __syncthreads();
        ts[tid] += t;
        __syncthreads();
    }
    int excl = ts[tid] - v;
    if (tid < nb) { base[tid] = excl; cursor[tid * CPAD] = excl; }
    if (tid == 255) { base[nb] = ts[255]; rowptr[n] = ts[255]; }
}

__global__ __launch_bounds__(256) void bin_scatter_kernel(const int* __restrict__ rows,
                                                          const int* __restrict__ cols,
                                                          const float* __restrict__ vals,
                                                          int ne,
                                                          int* __restrict__ cursor,
                                                          int nb,
                                                          int2* __restrict__ binned) {
    __shared__ int lcnt[NBB];
    __shared__ int lbase[NBB];
    const int tid = threadIdx.x;
    const int ce = (ne + gridDim.x - 1) / gridDim.x;
    const int e0 = blockIdx.x * ce;
    const int e1 = min(ne, e0 + ce);

    for (int i = tid; i < nb; i += 256) lcnt[i] = 0;
    __syncthreads();
    for (int e = e0 + tid; e < e1; e += 256) atomicAdd(&lcnt[rows[e] >> RSH], 1);
    __syncthreads();
    for (int b = tid; b < nb; b += 256) {
        int c = lcnt[b];
        lbase[b] = c ? atomicAdd(&cursor[b * CPAD], c) : 0;
    }
    __syncthreads();
    for (int i = tid; i < nb; i += 256) lcnt[i] = 0;   // reuse as local cursor
    __syncthreads();
    for (int e = e0 + tid; e < e1; e += 256) {
        int r = rows[e];
        int b = r >> RSH;
        int loc = atomicAdd(&lcnt[b], 1);
        int2 cv;
        cv.x = ((r & (RPB - 1)) << 17) | cols[e];
        cv.y = __float_as_int(vals[e]);
        binned[lbase[b] + loc] = cv;
    }
}

// ===========================================================================
// local_csr (R14-proven): grid = nb*4 blocks of 512 threads. Block (b,q):
// full 1024-bin hist of bucket b's segment, in-block scan, rowptr for its
// 2 bins/thread, then scatter ONLY quarter q's rows (256) into its
// contiguous window (streaming full-line writes, L2-resident).
// ===========================================================================
__global__ __launch_bounds__(512) void local_csr_kernel(const int* __restrict__ base,
                                                        const int2* __restrict__ binned,
                                                        int* __restrict__ rowptr,
                                                        int2* __restrict__ csr,
                                                        int n) {
    __shared__ int lh[RPB];     // hist -> cursor (4 KB)
    __shared__ int ts[512];
    const int tid = threadIdx.x;
    const int b = blockIdx.x >> 2;
    const int q = blockIdx.x & 3;
    const int jb = base[b], je = base[b + 1];

    lh[2 * tid] = 0; lh[2 * tid + 1] = 0;
    __syncthreads();
    for (int j = jb + tid; j < je; j += 512)
        atomicAdd(&lh[binned[j].x >> 17], 1);
    __syncthreads();

    const int v0 = lh[2 * tid], v1 = lh[2 * tid + 1];
    const int tsum = v0 + v1;
    ts[tid] = tsum;
    __syncthreads();
    for (int off = 1; off < 512; off <<= 1) {
        int t = (tid >= off) ? ts[tid - off] : 0;
        __syncthreads();
        ts[tid] += t;
        __syncthreads();
    }
    int excl = ts[tid] - tsum + jb;
    __syncthreads();           // everyone done reading lh as hist

    const int r0 = b * RPB + 2 * tid;
    lh[2 * tid] = excl;
    if (r0 < n) rowptr[r0] = excl;
    lh[2 * tid + 1] = excl + v0;
    if (r0 + 1 < n) rowptr[r0 + 1] = excl + v0;
    __syncthreads();

    for (int j = jb + tid; j < je; j += 512) {
        int2 e = binned[j];
        int rl = e.x >> 17;
        if ((rl >> 8) == q) {
            int pos = atomicAdd(&lh[rl], 1);
            int2 o; o.x = e.x & 0x1FFFF; o.y = e.y;
            csr[pos] = o;
        }
    }
}

// ===========================================================================
// Pull (R13): 2 rows per wave, uint (2 bf16) gathers, register accumulate,
// 8-deep unroll.
// ===========================================================================
__global__ __launch_bounds__(256) void pull2_kernel(const int* __restrict__ rowptr,
                                                    const int2* __restrict__ csr,
                                                    const unsigned int* __restrict__ sup32,
                                                    const float* __restrict__ bias,
                                                    float* __restrict__ out, int n) {
    const int tid  = threadIdx.x;
    const int lane = tid & 63;
    const int half = lane >> 5;
    const int sub  = lane & 31;
    const int wave = blockIdx.x * 4 + (tid >> 6);
    const int nwave = gridDim.x * 4;
    const float2 b2 = reinterpret_cast<const float2*>(bias)[sub];

    for (int w = wave; 2 * w < n; w += nwave) {
        const int r = 2 * w + half;
        float ax = 0.0f, ay = 0.0f;
        if (r < n) {
            const int jb = rowptr[r], je = rowptr[r + 1];
            int j = jb;
            for (; j + 7 < je; j += 8) {
                int2 e[8];
#pragma unroll
                for (int u = 0; u < 8; ++u) e[u] = csr[j + u];
                unsigned int g[8];
#pragma unroll
                for (int u = 0; u < 8; ++u)
                    g[u] = sup32[(size_t)e[u].x * 32 + sub];
#pragma unroll
                for (int u = 0; u < 8; ++u) {
                    float v = __int_as_float(e[u].y);
                    ax += v * __uint_as_float(g[u] << 16);
                    ay += v * __uint_as_float(g[u] & 0xffff0000u);
                }
            }
            for (; j + 1 < je; j += 2) {
                int2 e0 = csr[j], e1 = csr[j + 1];
                unsigned int u0 = sup32[(size_t)e0.x * 32 + sub];
                unsigned int u1 = sup32[(size_t)e1.x * 32 + sub];
                float v0 = __int_as_float(e0.y), v1 = __int_as_float(e1.y);
                ax += v0 * __uint_as_float(u0 << 16);
                ay += v0 * __uint_as_float(u0 & 0xffff0000u);
                ax += v1 * __uint_as_float(u1 << 16);
                ay += v1 * __uint_as_float(u1 & 0xffff0000u);
            }
            if (j < je) {
                int2 e = csr[j];
                unsigned int u = sup32[(size_t)e.x * 32 + sub];
                float v = __int_as_float(e.y);
                ax += v * __uint_as_float(u << 16);
                ay += v * __uint_as_float(u & 0xffff0000u);
            }
            float2 o; o.x = ax + b2.x; o.y = ay + b2.y;
            reinterpret_cast<float2*>(out)[(size_t)r * 32 + sub] = o;
        }
    }
}

// ===========================================================================
// Fallback (R1, verified): bias-init + atomic scatter (f32 support)
// ===========================================================================
__global__ __launch_bounds__(256) void init_kernel(const float* __restrict__ bias,
                                                   float* __restrict__ out, int total4) {
    int i = blockIdx.x * 256 + threadIdx.x;
    int stride = gridDim.x * 256;
    for (; i < total4; i += stride) {
        int base4 = (i * 4) & (D - 1);
        float4 bv;
        bv.x = bias[base4 + 0]; bv.y = bias[base4 + 1];
        bv.z = bias[base4 + 2]; bv.w = bias[base4 + 3];
        reinterpret_cast<float4*>(out)[i] = bv;
    }
}

__global__ __launch_bounds__(256) void scatter_kernel(const int* __restrict__ rows,
                                                      const int* __restrict__ cols,
                                                      const float* __restrict__ vals,
                                                      const float* __restrict__ support,
                                                      float* __restrict__ out, int ne) {
    const int wid  = blockIdx.x * 4 + (threadIdx.x >> 6);
    const int lane = threadIdx.x & 63;
    const int nw = gridDim.x * 4;
    for (int e = wid; e < ne; e += nw) {
        const int r = rows[e];
        const int c = cols[e];
        const float v = vals[e];
        unsafeAtomicAdd(&out[(size_t)r * D + lane], v * support[(size_t)c * D + lane]);
    }
}

extern "C" void kernel_launch(void* const* d_in, const int* in_sizes, int n_in,
                              void* d_out, int out_size, void* d_ws, size_t ws_size,
                              hipStream_t stream) {
    const float* x         = (const float*)d_in[0];
    const int*   edge_rows = (const int*)d_in[1];
    const int*   edge_cols = (const int*)d_in[2];
    const float* edge_vals = (const float*)d_in[3];
    const float* w_own     = (const float*)d_in[4];
    const float* w_nbr     = (const float*)d_in[5];
    const float* w_temp    = (const float*)d_in[6];
    const float* bias      = (const float*)d_in[7];

    float* out = (float*)d_out;
    const int n_nodes = in_sizes[0] / D;
    const int n_edges = in_sizes[1];
    const int nb = (n_nodes + RPB - 1) / RPB;

    // ---- workspace layout ----
    char* ws = (char*)d_ws;
    size_t off = 0;
    auto take = [&](size_t bytes) -> char* {
        char* p = ws + off;
        off = (off + bytes + 15) & ~(size_t)15;
        return p;
    };
    __hip_bfloat16* support = (__hip_bfloat16*)take((size_t)n_nodes * D * sizeof(__hip_bfloat16));
    int2* binned = (int2*)take((size_t)n_edges * sizeof(int2));
    int2* csr    = (int2*)take((size_t)n_edges * sizeof(int2));
    int*  rowptr = (int*) take((size_t)(n_nodes + 1) * sizeof(int));
    int*  gcnt   = (int*) take((size_t)nb * CPAD * sizeof(int));
    int*  base   = (int*) take((size_t)(nb + 1) * sizeof(int));
    int*  cursor = (int*) take((size_t)nb * CPAD * sizeof(int));
    const bool full_fits = (off <= ws_size) && (nb <= NBB) && (n_nodes <= (1 << 17));

    if (full_fits) {
        gemm_kernel<<<1024, 256, 0, stream>>>(x, w_own, w_nbr, w_temp, support, n_nodes);
        zero_kernel<<<8, 256, 0, stream>>>(gcnt, nb * CPAD);
        bucket_hist_kernel<<<512, 256, 0, stream>>>(edge_rows, n_edges, gcnt, nb);
        bucket_scan_kernel<<<1, 256, 0, stream>>>(gcnt, nb, base, cursor, rowptr, n_nodes);
        bin_scatter_kernel<<<512, 256, 0, stream>>>(edge_rows, edge_cols, edge_vals,
                                                    n_edges, cursor, nb, binned);
        local_csr_kernel<<<nb * 4, 512, 0, stream>>>(base, binned, rowptr, csr, n_nodes);
        pull2_kernel<<<2048, 256, 0, stream>>>(rowptr, csr, (const unsigned int*)support,
                                               bias, out, n_nodes);
    } else {
        // R1 fallback: f32 support + atomic scatter
        float* support_f = (float*)d_ws;
        gemm_f32_kernel<<<1024, 256, 0, stream>>>(x, w_own, w_nbr, w_temp, support_f, n_nodes);
        int total4 = (n_nodes * D) / 4;
        int blocks = (total4 + 255) / 256; if (blocks > 2048) blocks = 2048;
        init_kernel<<<blocks, 256, 0, stream>>>(bias, out, total4);
        scatter_kernel<<<2048, 256, 0, stream>>>(edge_rows, edge_cols, edge_vals,
                                                 support_f, out, n_edges);
    }
}